// Round 21
// baseline (128.096 us; speedup 1.0000x reference)
//
#include <hip/hip_runtime.h>

typedef float f32x4 __attribute__((ext_vector_type(4)));
typedef float f32x16v __attribute__((ext_vector_type(16)));
typedef __bf16 bf16x4 __attribute__((ext_vector_type(4)));
typedef __bf16 bf16x8 __attribute__((ext_vector_type(8)));

union U4B8 { uint4 u; bf16x8 b; };

// ws layout (bf16 elements): b2p[9216] @0, b3p[36864] @9216, c1p[1024] @46080
#define B2P_OFF 0
#define B3P_OFF 9216
#define C1P_OFF 46080

// ------------------------------------------------------------- pack_weights
// b2p frag f=t*2+p: lane l, j: oc=l&31, ic=(l>>5)*8+j              (32x32x16)
// b3p frag f=t*8+nt*2+p: lane l, j: oc=nt*16+(l&15), ic=(l>>4)*8+j (16x16x32)
// c1p (R19 mapping): A-frag = two horizontally-adjacent s_img cells.
__global__ __launch_bounds__(256) void pack_weights(
    const float* __restrict__ w1, const float* __restrict__ w2,
    const float* __restrict__ w3, __bf16* __restrict__ wsb) {
  int i = blockIdx.x * 256 + threadIdx.x;
  if (i < 9216) {
    int f = i >> 9, r = i & 511;
    int l = r >> 3, j = r & 7;
    int t = f >> 1, p = f & 1;
    int ky = t / 3, kx = t % 3;
    int oc = l & 31, ic = ((l >> 5) << 3) + j;
    float v = w2[oc * 144 + ic * 9 + ky * 3 + kx];
    __bf16 hi = (__bf16)v;
    wsb[B2P_OFF + i] = p ? (__bf16)(v - (float)hi) : hi;
  } else if (i < 9216 + 36864) {
    int q = i - 9216;
    int f = q >> 9, r = q & 511;
    int l = r >> 3, j = r & 7;
    int t = f >> 3, nt = (f >> 1) & 3, p = f & 1;
    int ky = t / 3, kx = t % 3;
    int oc = nt * 16 + (l & 15), ic = ((l >> 4) << 3) + j;
    float v = w3[oc * 288 + ic * 9 + ky * 3 + kx];
    __bf16 hi = (__bf16)v;
    wsb[B3P_OFF + q] = p ? (__bf16)(v - (float)hi) : hi;
  } else if (i < 9216 + 36864 + 1024) {
    int q = i - (9216 + 36864);
    int f = q >> 9, r = q & 511;
    int l = r >> 3, j = r & 7;
    int oc = l & 15, kg = l >> 4;
    int half = j >> 2, ic = j & 3;
    float v = 0.f;
    if (ic < 3) {
      if (f == 0) {
        if (kg < 3)            v = w1[oc * 27 + ic * 9 + kg * 3 + half];
        else if (half == 0)    v = w1[oc * 27 + ic * 9 + 0 * 3 + 2];
      } else {
        if (half == 0 && kg < 2) v = w1[oc * 27 + ic * 9 + (kg + 1) * 3 + 2];
      }
    }
    wsb[C1P_OFF + q] = (__bf16)v;
  }
}

// -------------------------------------------------------------- fused CNN
// R20 structure; launch_bounds (256,5): empirical reg budget ~256/minwaves
// -> ~51 regs (body compiles at 48, no spill) and guarantees 5 blocks/CU
// resident vs (256,4)'s 4. Bt loads hoisted above barrier 3b.
//   s_img @0 (9280B)  |  s2 @0 (16128B)  |  s3 @0 (8960B)
//   h3s @12288 (4096B, over dead s2 tail, disjoint from s3)
__global__ __launch_bounds__(256, 5) void cnn_fused(
    const float* __restrict__ x, const __bf16* __restrict__ wsb,
    const float* __restrict__ b1, const float* __restrict__ b2,
    const float* __restrict__ b3,
    const float* __restrict__ fcw, const float* __restrict__ fcb,
    float* __restrict__ out) {
  __shared__ __align__(16) unsigned char smem[16384];
  __bf16* s_img = (__bf16*)smem;
  __bf16* s2b   = (__bf16*)smem;
  __bf16* s3b   = (__bf16*)smem;
  float*  h3s   = (float*)(smem + 12288);

  const __bf16* b2p = wsb + B2P_OFF;
  const __bf16* b3p = wsb + B3P_OFF;
  const __bf16* c1p = wsb + C1P_OFF;

  const int tid = threadIdx.x;
  const int img = blockIdx.x;
  const int w = tid >> 6, lane = tid & 63;

  // ---- phase 1: halo zero (132 cells) + end pad + float4 staging
  if (tid < 132) {
    int row, col;
    if (tid < 34)       { row = 0;        col = tid; }
    else if (tid < 68)  { row = 33;       col = tid - 34; }
    else if (tid < 100) { row = tid - 67; col = 0; }
    else                { row = tid - 99; col = 33; }
    *(unsigned long long*)&s_img[(row * 34 + col) * 4] = 0ull;
  } else if (tid >= 248 && tid < 252) {
    *(unsigned long long*)&s_img[4624 + (tid - 248) * 4] = 0ull;  // pad
  }
  {
    const float* xg = x + img * 3072;
    const int r = tid * 4;
    const int y = r >> 5, xx = r & 31;
    const f32x4 c0 = *(const f32x4*)&xg[r];
    const f32x4 c1 = *(const f32x4*)&xg[r + 1024];
    const f32x4 c2 = *(const f32x4*)&xg[r + 2048];
    #pragma unroll
    for (int k = 0; k < 4; ++k) {
      bf16x4 pk;
      pk.x = (__bf16)c0[k];
      pk.y = (__bf16)c1[k];
      pk.z = (__bf16)c2[k];
      pk.w = (__bf16)0.f;
      *(bf16x4*)&s_img[((y + 1) * 34 + (xx + k + 1)) * 4] = pk;
    }
  }
  const bf16x8 B1h = *(const bf16x8*)(c1p + lane * 8);
  const bf16x8 B2h = *(const bf16x8*)(c1p + 512 + lane * 8);
  __syncthreads();                       // barrier 1: staging complete

  // ---- conv1: select-free A-build (R19-validated)
  float pooled[16];
  {
    const int xm = lane & 15, kg = lane >> 4;
    const int d1r = (kg == 3) ? 0 : kg;
    const int d1c = (kg == 3) ? 2 : 0;
    const int d2r = (kg == 0) ? 1 : 2;
    const int dd1 = d1r * 34 + d1c;
    const int dd2 = d2r * 34 + 2;
    #pragma unroll
    for (int p = 0; p < 4; ++p) {
      f32x4 acc[2][2];
      #pragma unroll
      for (int ys = 0; ys < 2; ++ys)
        #pragma unroll
        for (int xh = 0; xh < 2; ++xh)
          #pragma unroll
          for (int r = 0; r < 4; ++r) acc[ys][xh][r] = 0.f;
      #pragma unroll
      for (int ys = 0; ys < 2; ++ys) {
        const int yqg = w * 8 + p * 2 + ys;
        #pragma unroll
        for (int xh = 0; xh < 2; ++xh) {
          const int cb = yqg * 34 + xh * 16 + xm;
          const uint2 p0 = *(const uint2*)&s_img[(cb + dd1) * 4];
          const uint2 p1 = *(const uint2*)&s_img[(cb + dd1 + 1) * 4];
          const uint2 p2 = *(const uint2*)&s_img[(cb + dd2) * 4];
          const uint2 p3 = *(const uint2*)&s_img[(cb + dd2 + 1) * 4];
          U4B8 A1, A2;
          A1.u.x = p0.x; A1.u.y = p0.y; A1.u.z = p1.x; A1.u.w = p1.y;
          A2.u.x = p2.x; A2.u.y = p2.y; A2.u.z = p3.x; A2.u.w = p3.y;
          acc[ys][xh] = __builtin_amdgcn_mfma_f32_16x16x32_bf16(A1.b, B1h, acc[ys][xh], 0, 0, 0);
          acc[ys][xh] = __builtin_amdgcn_mfma_f32_16x16x32_bf16(A2.b, B2h, acc[ys][xh], 0, 0, 0);
        }
      }
      #pragma unroll
      for (int xh = 0; xh < 2; ++xh)
        #pragma unroll
        for (int xp2 = 0; xp2 < 2; ++xp2) {
          const float v0 = fmaxf(acc[0][xh][xp2 * 2], acc[0][xh][xp2 * 2 + 1]);
          const float v1 = fmaxf(acc[1][xh][xp2 * 2], acc[1][xh][xp2 * 2 + 1]);
          pooled[p * 4 + xh * 2 + xp2] = fmaxf(v0, v1);
        }
    }
  }
  __syncthreads();                       // barrier 2a: s_img dead (s2 overlays)

  // ---- h1 (bias+relu, bf16 hi only) -> s2 (row stride 448, cell 24)
  if (tid < 68) {
    int row, col;
    if (tid < 18)      { row = 0;       col = tid; }
    else if (tid < 36) { row = 17;      col = tid - 18; }
    else if (tid < 52) { row = tid - 35; col = 0; }
    else               { row = tid - 51; col = 17; }
    unsigned long long* p = (unsigned long long*)&s2b[row * 448 + col * 24];
    p[0] = 0ull; p[1] = 0ull; p[2] = 0ull; p[3] = 0ull;
  }
  {
    const int oc = lane & 15, quad = lane >> 4;
    const float bias = b1[oc];
    #pragma unroll
    for (int p = 0; p < 4; ++p)
      #pragma unroll
      for (int xh = 0; xh < 2; ++xh)
        #pragma unroll
        for (int xp2 = 0; xp2 < 2; ++xp2) {
          const float v = fmaxf(pooled[p * 4 + xh * 2 + xp2] + bias, 0.f);
          const int py = w * 4 + p, px = xh * 8 + quad * 2 + xp2;
          s2b[(py + 1) * 448 + (px + 1) * 24 + oc] = (__bf16)v;
        }
  }
  bf16x8 Bf[9];
  #pragma unroll
  for (int t = 0; t < 9; ++t)
    Bf[t] = *(const bf16x8*)(b2p + (t * 2) * 512 + lane * 8);
  __syncthreads();                       // barrier 2b: h1 complete

  // ---- conv2 (1-term), y-halves sequential
  float pooled2[8];
  {
    const unsigned short* s2 = (const unsigned short*)s2b;
    const int xm = lane & 15, yoff = (lane >> 4) & 1, kh = lane >> 5;
    #pragma unroll
    for (int i2 = 0; i2 < 2; ++i2) {
      f32x16v acc;
      #pragma unroll
      for (int r = 0; r < 16; ++r) acc[r] = 0.f;
      const int rbase = (4 * w + yoff + 2 * i2) * 448;
      #pragma unroll
      for (int t = 0; t < 9; ++t) {
        const int ky = t / 3, kx = t % 3;
        const int ro = rbase + ky * 448 + (xm + kx) * 24 + kh * 8;
        bf16x8 ah = *(const bf16x8*)&s2[ro];
        acc = __builtin_amdgcn_mfma_f32_32x32x16_bf16(ah, Bf[t], acc, 0, 0, 0);
      }
      #pragma unroll
      for (int bq = 0; bq < 2; ++bq)
        #pragma unroll
        for (int rq = 0; rq < 2; ++rq) {
          const int r0 = bq * 4 + rq * 2;
          pooled2[i2 * 4 + bq * 2 + rq] =
              fmaxf(fmaxf(acc[r0], acc[r0 + 1]), fmaxf(acc[r0 + 8], acc[r0 + 9]));
        }
    }
  }
  __syncthreads();                       // barrier 3a: s2 dead (s3 overlays)

  // ---- h2 (bias+relu, bf16 hi only) -> s3 (row stride 448, cell 40)
  if (tid < 36) {
    int row, col;
    if (tid < 10)      { row = 0;       col = tid; }
    else if (tid < 20) { row = 9;       col = tid - 10; }
    else if (tid < 28) { row = tid - 19; col = 0; }
    else               { row = tid - 27; col = 9; }
    unsigned long long* p = (unsigned long long*)&s3b[row * 448 + col * 40];
    #pragma unroll
    for (int u = 0; u < 8; ++u) p[u] = 0ull;
  }
  {
    const int oc = lane & 31, hh = lane >> 5;
    const float bias = b2[oc];
    #pragma unroll
    for (int i2 = 0; i2 < 2; ++i2)
      #pragma unroll
      for (int bq = 0; bq < 2; ++bq)
        #pragma unroll
        for (int rq = 0; rq < 2; ++rq) {
          const float v = fmaxf(pooled2[i2 * 4 + bq * 2 + rq] + bias, 0.f);
          const int py = 2 * w + i2, px = 2 * hh + 4 * bq + rq;
          s3b[(py + 1) * 448 + (px + 1) * 40 + oc] = (__bf16)v;
        }
  }
  // Bt loads hoisted here: overlap h2-write latency, no s3 dependency
  bf16x8 Bt[9];
  #pragma unroll
  for (int t = 0; t < 9; ++t)
    Bt[t] = *(const bf16x8*)(b3p + (t * 8 + w * 2) * 512 + lane * 8);
  __syncthreads();                       // barrier 3b: h2 complete

  // ---- conv3 (wave = nt = oc-tile), 1-term; h3s (@12288) disjoint from s3
  {
    const unsigned short* s3 = (const unsigned short*)s3b;
    const int nt = w;
    const int m = lane & 15, quad = lane >> 4;
    const int xm = m & 7, yoff = m >> 3;
    f32x4 acc[4];
    #pragma unroll
    for (int mt = 0; mt < 4; ++mt)
      #pragma unroll
      for (int r = 0; r < 4; ++r) acc[mt][r] = 0.f;
    #pragma unroll
    for (int t = 0; t < 9; ++t) {
      const int ky = t / 3, kx = t % 3;
      #pragma unroll
      for (int mt = 0; mt < 4; ++mt) {
        const int ro = (2 * mt + yoff + ky) * 448 + (xm + kx) * 40 + quad * 8;
        bf16x8 ah = *(const bf16x8*)&s3[ro];
        acc[mt] = __builtin_amdgcn_mfma_f32_16x16x32_bf16(ah, Bt[t], acc[mt], 0, 0, 0);
      }
    }
    const int ocl = lane & 15;
    #pragma unroll
    for (int mt = 0; mt < 4; ++mt) {
      float p0 = fmaxf(acc[mt][0], acc[mt][1]);
      float p1 = fmaxf(acc[mt][2], acc[mt][3]);
      p0 = fmaxf(p0, __shfl_xor(p0, 32, 64));
      p1 = fmaxf(p1, __shfl_xor(p1, 32, 64));
      if (quad < 2) {
        const int oc = nt * 16 + ocl;
        const float bias = b3[oc];
        const int base = oc * 16 + mt * 4 + (quad & 1) * 2;
        h3s[base]     = fmaxf(p0 + bias, 0.f);
        h3s[base + 1] = fmaxf(p1 + bias, 0.f);
      }
    }
  }
  __syncthreads();                       // barrier 4: h3 complete

  // ---- fc: lane owns 16 contiguous elements; 4x b128 LDS + 4x dwordx4/j
  {
    f32x4 hv[4];
    #pragma unroll
    for (int k = 0; k < 4; ++k) hv[k] = *(const f32x4*)&h3s[lane * 16 + k * 4];
    for (int j = w; j < 10; j += 4) {
      const f32x4* fw4 = (const f32x4*)&fcw[j * 1024 + lane * 16];
      float dot = 0.f;
      #pragma unroll
      for (int k = 0; k < 4; ++k) {
        const f32x4 fv = fw4[k];
        dot = fmaf(hv[k][0], fv[0], dot);
        dot = fmaf(hv[k][1], fv[1], dot);
        dot = fmaf(hv[k][2], fv[2], dot);
        dot = fmaf(hv[k][3], fv[3], dot);
      }
      #pragma unroll
      for (int s = 32; s > 0; s >>= 1) dot += __shfl_xor(dot, s, 64);
      if (lane == 0) out[img * 10 + j] = dot + fcb[j];
    }
  }
}

// -------------------------------------------------------------------- launch
extern "C" void kernel_launch(void* const* d_in, const int* in_sizes, int n_in,
                              void* d_out, int out_size, void* d_ws, size_t ws_size,
                              hipStream_t stream) {
  const float* x   = (const float*)d_in[0];
  const float* w1  = (const float*)d_in[1];
  const float* b1  = (const float*)d_in[2];
  const float* w2  = (const float*)d_in[3];
  const float* b2  = (const float*)d_in[4];
  const float* w3  = (const float*)d_in[5];
  const float* b3  = (const float*)d_in[6];
  const float* fcw = (const float*)d_in[7];
  const float* fcb = (const float*)d_in[8];
  __bf16* wsb = (__bf16*)d_ws;
  float* out = (float*)d_out;

  hipLaunchKernelGGL(pack_weights, dim3(184), dim3(256), 0, stream, w1, w2, w3, wsb);
  hipLaunchKernelGGL(cnn_fused, dim3(4096), dim3(256), 0, stream,
                     x, wsb, b1, b2, b3, fcw, fcb, out);
}